// Round 9
// baseline (285.174 us; speedup 1.0000x reference)
//
#include <hip/hip_runtime.h>

// ---------------------------------------------------------------------------
// SelfAttentionBlock: B=4, N=2048, D=1024.
//   QKV = X @ Wqkv^T                   (8192x1024)@(3072x1024)^T   [core B]
//   E_b = exp(Q_b @ K_b^T * 0.125)     bf16 + row-sum L (atomic)   [core B, fused]
//   V''_b = Wout @ V_b^T               (1024x2048) per batch       [core B, fused]
//   out_b = (E_b @ V''_b^T) / L + b    fp32                        [128² R1 core]
// R16: core B = R11's 256x128 block / 4 waves / wave 128x64 (0.75 LDS-reads
// per MFMA, vs 1.0 for the 64x64 wave tile) with the occupancy fix:
//  - fragments loaded PER k16-slice (24 live VGPR, was 96 up-front)
//  - no pointer arrays (base + seg*32*ld inline; uniform -> SGPR)
//  - __launch_bounds__(256,2): cap 256 unified regs -> 2 waves/SIMD
// Theory: all R2-R15 nulls (barriers, conflicts->0, dbuf, vmcnt, XCD) point
// at LDS-read-BW per MFMA as the binding resource; R11 had the right tile but
// 272 unified regs -> 1 wave/SIMD -> port starved (10.7% occ). This fits
// 128 AGPR + ~70 arch = ~200 <= 256.
// ---------------------------------------------------------------------------

typedef __bf16 bf16;
typedef __attribute__((ext_vector_type(8))) __bf16 bf16x8;
typedef __attribute__((ext_vector_type(4))) __bf16 bf16x4;
typedef __attribute__((ext_vector_type(16))) float f32x16;

#define BATCH 4
#define NTOK  2048
#define DIM   1024
#define MROWS (BATCH * NTOK)   // 8192
#define QKVC  (3 * DIM)        // 3072

__device__ __forceinline__ void async16(const bf16* g, bf16* l) {
  __builtin_amdgcn_global_load_lds(
      (const __attribute__((address_space(1))) void*)g,
      (__attribute__((address_space(3))) void*)l, 16, 0, 0);
}

// ---------------------------------------------------------------------------
// prep: three fp32->bf16 converts + L zero
// ---------------------------------------------------------------------------
__device__ __forceinline__ void cvt4(const float* in, bf16* out, int i4) {
  float4 f = *(const float4*)(in + i4 * 4);
  bf16x4 o;
  o.x = (bf16)f.x; o.y = (bf16)f.y; o.z = (bf16)f.z; o.w = (bf16)f.w;
  *(bf16x4*)(out + i4 * 4) = o;
}

__global__ void prep(const float* __restrict__ x, const float* __restrict__ wqkv,
                     const float* __restrict__ wout,
                     bf16* __restrict__ Xbf, bf16* __restrict__ Wqkvb,
                     bf16* __restrict__ Woutb, float* __restrict__ L) {
  const int nx = MROWS * DIM / 4, nq = QKVC * DIM / 4, nw = DIM * DIM / 4;
  const int nl = BATCH * NTOK / 4;
  int i = blockIdx.x * blockDim.x + threadIdx.x;
  if (i < nx) cvt4(x, Xbf, i);
  else if (i < nx + nq) cvt4(wqkv, Wqkvb, i - nx);
  else if (i < nx + nq + nw) cvt4(wout, Woutb, i - nx - nq);
  else if (i < nx + nq + nw + nl) {
    float4 z = {0.f, 0.f, 0.f, 0.f};
    *(float4*)(L + (i - nx - nq - nw) * 4) = z;
  }
}

// ===========================================================================
// Core B: 256(M) x 128(N) block, BK=64, 4 waves as 2(M)x2(N), wave 128x64 =
// 4x2 of 32x32x16 MFMA, acc[4][2] (128 AGPR). Fragments per k16-slice.
// LDS: As[256][64] (32 KB) + Bs[128][64] (16 KB) = 48 KB -> 2 blocks/CU.
// Row = 8 chunks of 8 bf16; physical slot c of row r holds global chunk
// c^(r&7); staging tid->row=tid>>3 (+32*seg), slot=tid&7; swizzle applied on
// the GLOBAL source col so global_load_lds dst stays linear (tid*16).
// A-frag: A[m=lane&31][k=8*(lane>>5)+e]; C/D: col=lane&31,
// row=(reg&3)+8*(reg>>2)+4*(lane>>5).   [R11/R4-verified algebra]
// ===========================================================================
__device__ __forceinline__ void coreB_kloop(
    const bf16* __restrict__ gA, const bf16* __restrict__ gB,
    long ldaL, long ldbL, int K,
    bf16* As, bf16* Bs, int s0, int wm, int wn, int l31, int half,
    f32x16 acc[4][2]) {
  const int sw = l31 & 7;
  for (int kt = 0; kt < K; kt += 64) {
#pragma unroll
    for (int seg = 0; seg < 8; ++seg)
      async16(gA + (long)(32 * seg) * ldaL + kt, As + s0 + seg * 2048);
#pragma unroll
    for (int seg = 0; seg < 4; ++seg)
      async16(gB + (long)(32 * seg) * ldbL + kt, Bs + s0 + seg * 2048);
    __syncthreads();

#pragma unroll
    for (int ks = 0; ks < 4; ++ks) {
      const int slot = ((ks * 2 + half) ^ sw) * 8;
      bf16x8 af[4], bf[2];
#pragma unroll
      for (int ti = 0; ti < 4; ++ti)
        af[ti] = *(const bf16x8*)&As[(wm + ti * 32 + l31) * 64 + slot];
#pragma unroll
      for (int tj = 0; tj < 2; ++tj)
        bf[tj] = *(const bf16x8*)&Bs[(wn + tj * 32 + l31) * 64 + slot];
#pragma unroll
      for (int ti = 0; ti < 4; ++ti)
#pragma unroll
        for (int tj = 0; tj < 2; ++tj)
          acc[ti][tj] = __builtin_amdgcn_mfma_f32_32x32x16_bf16(
              af[ti], bf[tj], acc[ti][tj], 0, 0, 0);
    }

    __syncthreads();
  }
}

// ---- QKV = X @ Wqkv^T (core B), bf16 out -----------------------------------
__launch_bounds__(256, 2)
__global__ void gemm_qkv(const bf16* __restrict__ Xb, const bf16* __restrict__ Wq,
                         bf16* __restrict__ QKV) {
  __shared__ alignas(16) bf16 As[256 * 64];
  __shared__ alignas(16) bf16 Bs[128 * 64];
  const int tid = threadIdx.x, wave = tid >> 6, lane = tid & 63;
  const int wm = (wave >> 1) * 128, wn = (wave & 1) * 64;
  const int l31 = lane & 31, half = lane >> 5;
  const int srow = tid >> 3, sc = tid & 7;
  const int scol = (sc ^ (srow & 7)) << 3;
  const int s0 = srow * 64 + sc * 8;

  const long rowA = (long)blockIdx.y * 256;
  const long rowB = (long)blockIdx.x * 128;
  const bf16* gA = Xb + (rowA + srow) * (long)DIM + scol;
  const bf16* gB = Wq + (rowB + srow) * (long)DIM + scol;

  f32x16 acc[4][2] = {};
  coreB_kloop(gA, gB, DIM, DIM, DIM, As, Bs, s0, wm, wn, l31, half, acc);

#pragma unroll
  for (int ti = 0; ti < 4; ++ti)
#pragma unroll
    for (int tj = 0; tj < 2; ++tj) {
      const long col = rowB + wn + tj * 32 + l31;
#pragma unroll
      for (int r = 0; r < 16; ++r) {
        const long row = rowA + wm + ti * 32 + (r & 3) + 8 * (r >> 2) + 4 * half;
        QKV[row * (long)QKVC + col] = (bf16)acc[ti][tj][r];
      }
    }
}

// ---- fused (core B): z<4 -> E_b = exp(QK^T/8)+L ; z>=4 -> V'' = Wout@V^T ---
__launch_bounds__(256, 2)
__global__ void gemm_sv(const bf16* __restrict__ QKV, const bf16* __restrict__ Wout,
                        bf16* __restrict__ E, bf16* __restrict__ Vpp,
                        float* __restrict__ Lroot) {
  __shared__ alignas(16) bf16 As[256 * 64];
  __shared__ alignas(16) bf16 Bs[128 * 64];
  const int tid = threadIdx.x, wave = tid >> 6, lane = tid & 63;
  const int wm = (wave >> 1) * 128, wn = (wave & 1) * 64;
  const int l31 = lane & 31, half = lane >> 5;
  const int srow = tid >> 3, sc = tid & 7;
  const int scol = (sc ^ (srow & 7)) << 3;
  const int s0 = srow * 64 + sc * 8;
  const int z = blockIdx.z;

  if (z < 4) {
    // ---- E-GEMM: A=Q, B=K rows of QKV batch z ----
    const bf16* A  = QKV + (long)z * NTOK * QKVC;
    const long rowA = (long)blockIdx.y * 256;
    const long rowB = (long)blockIdx.x * 128;
    const bf16* gA = A + (rowA + srow) * (long)QKVC + scol;
    const bf16* gB = A + DIM + (rowB + srow) * (long)QKVC + scol;
    f32x16 acc[4][2] = {};
    coreB_kloop(gA, gB, QKVC, QKVC, DIM, As, Bs, s0, wm, wn, l31, half, acc);

    bf16* C = E + (long)z * NTOK * NTOK;
    float* L = Lroot + (long)z * NTOK;
#pragma unroll
    for (int ti = 0; ti < 4; ++ti) {
#pragma unroll
      for (int r = 0; r < 16; ++r) {
        const long row = rowA + wm + ti * 32 + (r & 3) + 8 * (r >> 2) + 4 * half;
        float psum = 0.f;
#pragma unroll
        for (int tj = 0; tj < 2; ++tj) {
          const long col = rowB + wn + tj * 32 + l31;
          float e = __expf(acc[ti][tj][r] * 0.125f);
          bf16 eb = (bf16)e;
          C[row * (long)NTOK + col] = eb;
          psum += (float)eb;   // sum what downstream consumes
        }
#pragma unroll
        for (int off = 16; off >= 1; off >>= 1) psum += __shfl_xor(psum, off, 64);
        if (l31 == 0) atomicAdd(&L[row], psum);
      }
    }
  } else {
    if (blockIdx.y >= 4) return;   // V'' has 1024 rows = 4 tiles of 256
    const int b = z - 4;
    const bf16* Bq = QKV + (long)b * NTOK * QKVC + 2 * DIM;
    const long rowA = (long)blockIdx.y * 256;
    const long rowB = (long)blockIdx.x * 128;
    const bf16* gA = Wout + (rowA + srow) * (long)DIM + scol;
    const bf16* gB = Bq + (rowB + srow) * (long)QKVC + scol;
    f32x16 acc[4][2] = {};
    coreB_kloop(gA, gB, DIM, QKVC, DIM, As, Bs, s0, wm, wn, l31, half, acc);

    bf16* C = Vpp + (long)b * DIM * NTOK;
#pragma unroll
    for (int ti = 0; ti < 4; ++ti)
#pragma unroll
      for (int tj = 0; tj < 2; ++tj) {
        const long col = rowB + wn + tj * 32 + l31;
#pragma unroll
        for (int r = 0; r < 16; ++r) {
          const long row = rowA + wm + ti * 32 + (r & 3) + 8 * (r >> 2) + 4 * half;
          C[row * (long)NTOK + col] = (bf16)acc[ti][tj][r];
        }
      }
  }
}

// ===========================================================================
// 128² R1 core (proven) for the out-GEMM (512 blocks, 2/CU).
// ===========================================================================
struct GemmCore {
  const bf16 *ga[4], *gb[4];
  int sIdx[4];
  int wm, wn, l31, half;
};

__device__ __forceinline__ GemmCore gemm_setup(const bf16* A, const bf16* Bm,
                                               int lda, int ldb,
                                               long rowA, long rowB) {
  GemmCore g;
  const int tid = threadIdx.x;
  const int wave = tid >> 6, lane = tid & 63;
  g.wm = (wave >> 1) << 6;
  g.wn = (wave & 1) << 6;
  g.l31 = lane & 31;
  g.half = lane >> 5;
  const int srow = tid >> 3;
  const int sc   = tid & 7;
  const int scol = (sc ^ (srow & 7)) << 3;
#pragma unroll
  for (int seg = 0; seg < 4; ++seg) {
    g.ga[seg] = A  + (rowA + srow + 32 * seg) * (long)lda + scol;
    g.gb[seg] = Bm + (rowB + srow + 32 * seg) * (long)ldb + scol;
    g.sIdx[seg] = (srow + 32 * seg) * 64 + sc * 8;
  }
  return g;
}

__device__ __forceinline__ void gemm_kloop(const GemmCore& g, int K,
                                           bf16* As, bf16* Bs, f32x16 acc[2][2]) {
  const int sw = g.l31 & 7;
  for (int kt = 0; kt < K; kt += 64) {
#pragma unroll
    for (int seg = 0; seg < 4; ++seg) {
      async16(g.ga[seg] + kt, As + g.sIdx[seg]);
      async16(g.gb[seg] + kt, Bs + g.sIdx[seg]);
    }
    __syncthreads();

    bf16x8 af[2][4], bfm[2][4];
#pragma unroll
    for (int ti = 0; ti < 2; ++ti)
#pragma unroll
      for (int s = 0; s < 4; ++s)
        af[ti][s] = *(const bf16x8*)&As[(g.wm + ti * 32 + g.l31) * 64 + ((s * 2 + g.half) ^ sw) * 8];
#pragma unroll
    for (int tj = 0; tj < 2; ++tj)
#pragma unroll
      for (int s = 0; s < 4; ++s)
        bfm[tj][s] = *(const bf16x8*)&Bs[(g.wn + tj * 32 + g.l31) * 64 + ((s * 2 + g.half) ^ sw) * 8];

#pragma unroll
    for (int s = 0; s < 4; ++s)
#pragma unroll
      for (int ti = 0; ti < 2; ++ti)
#pragma unroll
        for (int tj = 0; tj < 2; ++tj)
          acc[ti][tj] = __builtin_amdgcn_mfma_f32_32x32x16_bf16(
              af[ti][s], bfm[tj][s], acc[ti][tj], 0, 0, 0);

    __syncthreads();
  }
}

// out_b = (E_b @ V''_b^T)/L + bias  (fp32 store)
__launch_bounds__(256)
__global__ void gemm_out(const bf16* __restrict__ Eroot, const bf16* __restrict__ Vroot,
                         float* __restrict__ Croot, const float* __restrict__ bias,
                         const float* __restrict__ Lroot) {
  const bf16* A  = Eroot + (long)blockIdx.z * NTOK * NTOK;
  const bf16* Bm = Vroot + (long)blockIdx.z * DIM * NTOK;
  __shared__ alignas(16) bf16 As[128 * 64];
  __shared__ alignas(16) bf16 Bs[128 * 64];

  const long rowA = (long)blockIdx.y * 128;
  const long rowB = (long)blockIdx.x * 128;
  GemmCore g = gemm_setup(A, Bm, NTOK, NTOK, rowA, rowB);

  f32x16 acc[2][2] = {};
  gemm_kloop(g, NTOK, As, Bs, acc);

  float* C = Croot + (long)blockIdx.z * NTOK * DIM;
  const float* L = Lroot + (long)blockIdx.z * NTOK;
#pragma unroll
  for (int ti = 0; ti < 2; ++ti) {
#pragma unroll
    for (int r = 0; r < 16; ++r) {
      const long row = rowA + g.wm + ti * 32 + (r & 3) + 8 * (r >> 2) + 4 * g.half;
      const float inv = 1.0f / L[row];
#pragma unroll
      for (int tj = 0; tj < 2; ++tj) {
        const long col = rowB + g.wn + tj * 32 + g.l31;
        C[row * (long)DIM + col] = acc[ti][tj][r] * inv + bias[col];
      }
    }
  }
}

// ---------------------------------------------------------------------------
extern "C" void kernel_launch(void* const* d_in, const int* in_sizes, int n_in,
                              void* d_out, int out_size, void* d_ws, size_t ws_size,
                              hipStream_t stream) {
  const float* x      = (const float*)d_in[0];   // (4,2048,1024)
  const float* w_qkv  = (const float*)d_in[1];   // (3072,1024)
  const float* w_out  = (const float*)d_in[2];   // (1024,1024)
  const float* b_out  = (const float*)d_in[3];   // (1024,)
  float* out = (float*)d_out;                    // (4,2048,1024) fp32

  // workspace layout (bytes) — total ~120 MiB
  char* w = (char*)d_ws;
  bf16*  Xbf   = (bf16*)(w);                          // 8192*1024*2   = 16 MiB
  bf16*  Wqkvb = (bf16*)(w + 16777216);               // 3072*1024*2   =  6 MiB
  bf16*  Woutb = (bf16*)(w + 23068672);               // 1024*1024*2   =  2 MiB
  bf16*  QKV   = (bf16*)(w + 25165824);               // 8192*3072*2   = 48 MiB
  bf16*  E     = (bf16*)(w + 75497472);               // 4*2048*2048*2 = 32 MiB
  bf16*  Vpp   = (bf16*)(w + 109051904);              // 4*1024*2048*2 = 16 MiB
  float* L     = (float*)(w + 125829120);             // 4*2048*4      = 32 KiB

  // 1) one prep dispatch: converts + L zero
  {
    const int n4 = MROWS * DIM / 4 + QKVC * DIM / 4 + DIM * DIM / 4 + BATCH * NTOK / 4;
    prep<<<(n4 + 255) / 256, 256, 0, stream>>>(x, w_qkv, w_out, Xbf, Wqkvb, Woutb, L);
  }

  // 2) QKV = X @ Wqkv^T -> bf16 (8192 x 3072); core B: 24x32 = 768 blocks
  gemm_qkv<<<dim3(QKVC / 128, MROWS / 256, 1), 256, 0, stream>>>(Xbf, Wqkvb, QKV);

  // 3) fused: E (512 blocks) + V'' (256 blocks); core B
  gemm_sv<<<dim3(NTOK / 128, NTOK / 256, 2 * BATCH), 256, 0, stream>>>(
      QKV, Woutb, E, Vpp, L);

  // 4) out_b = (E_b @ V''_b^T)/L + b_out -> fp32; 512 blocks, 128² core
  gemm_out<<<dim3(DIM / 128, NTOK / 128, BATCH), 256, 0, stream>>>(
      E, Vpp, out, b_out, L);
}

// Round 10
// 277.160 us; speedup vs baseline: 1.0289x; 1.0289x over previous
//
#include <hip/hip_runtime.h>

// ---------------------------------------------------------------------------
// SelfAttentionBlock: B=4, N=2048, D=1024. Single-head attention, head dim 1024.
//   QKV = X @ Wqkv^T                   (8192x1024)@(3072x1024)^T
//   E_b = exp(Q_b @ K_b^T * 0.125)     bf16, fused epilogue, row sums L (atomic)
//   V''_b = Wout @ V_b^T               (1024x2048) per batch
//   out_b = (E_b @ V''_b^T) / L + b    fp32
// R17: R1 skeleton (128x128 / BK=64 / 1-phase / 32 KiB LDS / 3D grids) with
// MFMA 32x32x16 -> 16x16x32. Same wave tile 64x64 (now 4x4 of 16x16), same
// LDS traffic (16 ds_read_b128 per K-tile), but acc = 64 AGPR (was 128).
// Unified regs ~80+64=144 -> 3 waves/SIMD, 3 blocks/CU — first variant above
// 2. Occupancy ledger: R1-R16 all had 128-AGPR acc -> <=2 waves/SIMD, and
// perf tracked occupancy monotonically (27/19.5/16.5/10.7% -> 76/81/84/113us)
// => latency-bound; this buys +50% resident waves at ~13% MFMA-rate cost
// (irrelevant at 28% MfmaUtil).
// 16x16x32 bf16 layouts (m89-verified): A/B lane l: m(or n)=l&15,
// k=8*(l>>4)+e. C/D: col=l&15, row=(l>>4)*4+r.
// ---------------------------------------------------------------------------

typedef __bf16 bf16;
typedef __attribute__((ext_vector_type(8))) __bf16 bf16x8;
typedef __attribute__((ext_vector_type(4))) __bf16 bf16x4;
typedef __attribute__((ext_vector_type(4))) float f32x4;

#define BATCH 4
#define NTOK  2048
#define DIM   1024
#define MROWS (BATCH * NTOK)   // 8192
#define QKVC  (3 * DIM)        // 3072

__device__ __forceinline__ void async16(const bf16* g, bf16* l) {
  __builtin_amdgcn_global_load_lds(
      (const __attribute__((address_space(1))) void*)g,
      (__attribute__((address_space(3))) void*)l, 16, 0, 0);
}

// ---------------------------------------------------------------------------
// one prep kernel: three fp32->bf16 converts + L zero
// ---------------------------------------------------------------------------
__device__ __forceinline__ void cvt4(const float* in, bf16* out, int i4) {
  float4 f = *(const float4*)(in + i4 * 4);
  bf16x4 o;
  o.x = (bf16)f.x; o.y = (bf16)f.y; o.z = (bf16)f.z; o.w = (bf16)f.w;
  *(bf16x4*)(out + i4 * 4) = o;
}

__global__ void prep(const float* __restrict__ x, const float* __restrict__ wqkv,
                     const float* __restrict__ wout,
                     bf16* __restrict__ Xbf, bf16* __restrict__ Wqkvb,
                     bf16* __restrict__ Woutb, float* __restrict__ L) {
  const int nx = MROWS * DIM / 4, nq = QKVC * DIM / 4, nw = DIM * DIM / 4;
  const int nl = BATCH * NTOK / 4;
  int i = blockIdx.x * blockDim.x + threadIdx.x;
  if (i < nx) cvt4(x, Xbf, i);
  else if (i < nx + nq) cvt4(wqkv, Wqkvb, i - nx);
  else if (i < nx + nq + nw) cvt4(wout, Woutb, i - nx - nq);
  else if (i < nx + nq + nw + nl) {
    float4 z = {0.f, 0.f, 0.f, 0.f};
    *(float4*)(L + (i - nx - nq - nw) * 4) = z;
  }
}

// ---------------------------------------------------------------------------
// GEMM core. C[i][j] = sum_k A[i][k] * B[j][k] (B^T pattern). BK=64.
// 16x16x32 MFMA, 4 waves 2x2, wave 64x64 = 4x4 of 16x16. acc[4][4] f32x4
// (64 AGPR). Per K-tile: 2 k32-steps x (4 A + 4 B ds_read_b128 + 16 MFMA).
// LDS tile [128 rows][64 k], 128B rows = 8 chunks; slot c of row r holds
// global chunk c^(r&7). Staging: tid -> row=tid>>3 (+32*seg), slot=tid&7;
// swizzle applied on GLOBAL source col so global_load_lds dst stays linear.
// Read: row = wm + ti*16 + (l&15) -> row&7 = l&7 = sw; global chunk
// g = ks*4 + (l>>4) -> physical slot g^sw.
// ---------------------------------------------------------------------------
struct GemmCore {
  const bf16 *ga[4], *gb[4];
  int sIdx[4];
  int wm, wn, l15, kq;
};

__device__ __forceinline__ GemmCore gemm_setup(const bf16* A, const bf16* Bm,
                                               int lda, int ldb,
                                               long rowA, long rowB) {
  GemmCore g;
  const int tid = threadIdx.x;
  const int wave = tid >> 6, lane = tid & 63;
  g.wm = (wave >> 1) << 6;
  g.wn = (wave & 1) << 6;
  g.l15 = lane & 15;
  g.kq  = lane >> 4;                       // 0..3
  const int srow = tid >> 3;               // 0..31
  const int sc   = tid & 7;                // physical slot
  const int scol = (sc ^ (srow & 7)) << 3; // swizzled global chunk * 8
#pragma unroll
  for (int seg = 0; seg < 4; ++seg) {
    g.ga[seg] = A  + (rowA + srow + 32 * seg) * (long)lda + scol;
    g.gb[seg] = Bm + (rowB + srow + 32 * seg) * (long)ldb + scol;
    g.sIdx[seg] = (srow + 32 * seg) * 64 + sc * 8;
  }
  return g;
}

__device__ __forceinline__ void gemm_kloop(const GemmCore& g, int K,
                                           bf16* As, bf16* Bs, f32x4 acc[4][4]) {
  const int sw = g.l15 & 7;
  for (int kt = 0; kt < K; kt += 64) {
#pragma unroll
    for (int seg = 0; seg < 4; ++seg) {
      async16(g.ga[seg] + kt, As + g.sIdx[seg]);
      async16(g.gb[seg] + kt, Bs + g.sIdx[seg]);
    }
    __syncthreads();

#pragma unroll
    for (int ks = 0; ks < 2; ++ks) {
      const int slot = ((ks * 4 + g.kq) ^ sw) * 8;
      bf16x8 af[4], bfm[4];
#pragma unroll
      for (int ti = 0; ti < 4; ++ti)
        af[ti] = *(const bf16x8*)&As[(g.wm + ti * 16 + g.l15) * 64 + slot];
#pragma unroll
      for (int tj = 0; tj < 4; ++tj)
        bfm[tj] = *(const bf16x8*)&Bs[(g.wn + tj * 16 + g.l15) * 64 + slot];
#pragma unroll
      for (int ti = 0; ti < 4; ++ti)
#pragma unroll
        for (int tj = 0; tj < 4; ++tj)
          acc[ti][tj] = __builtin_amdgcn_mfma_f32_16x16x32_bf16(
              af[ti], bfm[tj], acc[ti][tj], 0, 0, 0);
    }

    __syncthreads();
  }
}

// ---------------------------------------------------------------------------
// Plain GEMMs. MODE 0: store bf16. MODE 2: store fp32 v/L[row] + bias[col].
// ---------------------------------------------------------------------------
template <int MODE>
__launch_bounds__(256)
__global__ void gemm_bt(const bf16* __restrict__ Aroot, const bf16* __restrict__ Broot,
                        void* __restrict__ Croot, const float* __restrict__ bias,
                        const float* __restrict__ Lroot,
                        int K, int lda, int ldb, int ldc,
                        long strideA, long strideB, long strideC) {
  const bf16* A  = Aroot + (long)blockIdx.z * strideA;
  const bf16* Bm = Broot + (long)blockIdx.z * strideB;
  __shared__ alignas(16) bf16 As[128 * 64];
  __shared__ alignas(16) bf16 Bs[128 * 64];

  const long rowA = (long)blockIdx.y * 128;
  const long rowB = (long)blockIdx.x * 128;
  GemmCore g = gemm_setup(A, Bm, lda, ldb, rowA, rowB);

  f32x4 acc[4][4] = {};
  gemm_kloop(g, K, As, Bs, acc);

  if constexpr (MODE == 0) {
    bf16* C = (bf16*)Croot + (long)blockIdx.z * strideC;
#pragma unroll
    for (int ti = 0; ti < 4; ++ti)
#pragma unroll
      for (int tj = 0; tj < 4; ++tj) {
        const long col = rowB + g.wn + tj * 16 + g.l15;
#pragma unroll
        for (int r = 0; r < 4; ++r) {
          const long row = rowA + g.wm + ti * 16 + g.kq * 4 + r;
          C[row * (long)ldc + col] = (bf16)acc[ti][tj][r];
        }
      }
  } else {
    float* C = (float*)Croot + (long)blockIdx.z * strideC;
    const float* L = Lroot + (long)blockIdx.z * NTOK;
#pragma unroll
    for (int ti = 0; ti < 4; ++ti) {
#pragma unroll
      for (int r = 0; r < 4; ++r) {
        const long row = rowA + g.wm + ti * 16 + g.kq * 4 + r;
        const float inv = 1.0f / L[row];
#pragma unroll
        for (int tj = 0; tj < 4; ++tj) {
          const long col = rowB + g.wn + tj * 16 + g.l15;
          C[row * (long)ldc + col] = acc[ti][tj][r] * inv + bias[col];
        }
      }
    }
  }
}

// ---------------------------------------------------------------------------
// Fused dispatch: z<4 -> E_b = exp(Q_b@K_b^T/8) + row-sum L (batch z);
//                 z>=4 -> V''_b = Wout @ V_b^T (batch z-4; blockIdx.y>=8 idle).
// ---------------------------------------------------------------------------
__launch_bounds__(256)
__global__ void gemm_sv(const bf16* __restrict__ QKV, const bf16* __restrict__ Wout,
                        bf16* __restrict__ E, bf16* __restrict__ Vpp,
                        float* __restrict__ Lroot) {
  __shared__ alignas(16) bf16 As[128 * 64];
  __shared__ alignas(16) bf16 Bs[128 * 64];

  const int z = blockIdx.z;
  if (z < 4) {
    // ---- E-GEMM: A=Q, B=K rows of QKV batch z ----
    const bf16* A  = QKV + (long)z * NTOK * QKVC;
    const bf16* Bm = A + DIM;
    const long rowA = (long)blockIdx.y * 128;
    const long rowB = (long)blockIdx.x * 128;
    GemmCore g = gemm_setup(A, Bm, QKVC, QKVC, rowA, rowB);
    f32x4 acc[4][4] = {};
    gemm_kloop(g, DIM, As, Bs, acc);

    bf16* C = E + (long)z * NTOK * NTOK;
    float* L = Lroot + (long)z * NTOK;
#pragma unroll
    for (int ti = 0; ti < 4; ++ti) {
#pragma unroll
      for (int r = 0; r < 4; ++r) {
        const long row = rowA + g.wm + ti * 16 + g.kq * 4 + r;
        float psum = 0.f;
#pragma unroll
        for (int tj = 0; tj < 4; ++tj) {
          const long col = rowB + g.wn + tj * 16 + g.l15;
          float e = __expf(acc[ti][tj][r] * 0.125f);
          bf16 eb = (bf16)e;
          C[row * (long)NTOK + col] = eb;
          psum += (float)eb;   // sum what downstream consumes
        }
        // reduce over the 16-lane group (same row: lanes differ in l15 only)
#pragma unroll
        for (int off = 8; off >= 1; off >>= 1) psum += __shfl_xor(psum, off, 64);
        if (g.l15 == 0) atomicAdd(&L[row], psum);
      }
    }
  } else {
    if (blockIdx.y >= 8) return;   // V'' output is 1024 rows = 8 row-tiles
    // ---- V''-GEMM: A=Wout (1024x1024), B=V rows of QKV batch z-4 ----
    const int b = z - 4;
    const bf16* Bm = QKV + (long)b * NTOK * QKVC + 2 * DIM;
    const long rowA = (long)blockIdx.y * 128;
    const long rowB = (long)blockIdx.x * 128;
    GemmCore g = gemm_setup(Wout, Bm, DIM, QKVC, rowA, rowB);
    f32x4 acc[4][4] = {};
    gemm_kloop(g, DIM, As, Bs, acc);

    bf16* C = Vpp + (long)b * DIM * NTOK;
#pragma unroll
    for (int ti = 0; ti < 4; ++ti)
#pragma unroll
      for (int tj = 0; tj < 4; ++tj) {
        const long col = rowB + g.wn + tj * 16 + g.l15;
#pragma unroll
        for (int r = 0; r < 4; ++r) {
          const long row = rowA + g.wm + ti * 16 + g.kq * 4 + r;
          C[row * (long)NTOK + col] = (bf16)acc[ti][tj][r];
        }
      }
  }
}

// ---------------------------------------------------------------------------
extern "C" void kernel_launch(void* const* d_in, const int* in_sizes, int n_in,
                              void* d_out, int out_size, void* d_ws, size_t ws_size,
                              hipStream_t stream) {
  const float* x      = (const float*)d_in[0];   // (4,2048,1024)
  const float* w_qkv  = (const float*)d_in[1];   // (3072,1024)
  const float* w_out  = (const float*)d_in[2];   // (1024,1024)
  const float* b_out  = (const float*)d_in[3];   // (1024,)
  float* out = (float*)d_out;                    // (4,2048,1024) fp32

  // workspace layout (bytes) — total ~120 MiB
  char* w = (char*)d_ws;
  bf16*  Xbf   = (bf16*)(w);                          // 8192*1024*2   = 16 MiB
  bf16*  Wqkvb = (bf16*)(w + 16777216);               // 3072*1024*2   =  6 MiB
  bf16*  Woutb = (bf16*)(w + 23068672);               // 1024*1024*2   =  2 MiB
  bf16*  QKV   = (bf16*)(w + 25165824);               // 8192*3072*2   = 48 MiB
  bf16*  E     = (bf16*)(w + 75497472);               // 4*2048*2048*2 = 32 MiB
  bf16*  Vpp   = (bf16*)(w + 109051904);              // 4*1024*2048*2 = 16 MiB
  float* L     = (float*)(w + 125829120);             // 4*2048*4      = 32 KiB

  // 1) one prep dispatch: converts + L zero
  {
    const int n4 = MROWS * DIM / 4 + QKVC * DIM / 4 + DIM * DIM / 4 + BATCH * NTOK / 4;
    prep<<<(n4 + 255) / 256, 256, 0, stream>>>(x, w_qkv, w_out, Xbf, Wqkvb, Woutb, L);
  }

  // 2) QKV = X @ Wqkv^T -> bf16 (8192 x 3072)
  gemm_bt<0><<<dim3(QKVC / 128, MROWS / 128, 1), 256, 0, stream>>>(
      Xbf, Wqkvb, QKV, nullptr, nullptr, DIM, DIM, DIM, QKVC, 0, 0, 0);

  // 3) fused: E_b = exp(Q_b@K_b^T/8) + L row-sums  AND  V''_b = Wout @ V_b^T
  gemm_sv<<<dim3(NTOK / 128, NTOK / 128, 2 * BATCH), 256, 0, stream>>>(
      QKV, Woutb, E, Vpp, L);

  // 4) out_b = (E_b @ V''_b^T) / L + b_out -> fp32 (2048 x 1024 per batch)
  gemm_bt<2><<<dim3(DIM / 128, NTOK / 128, BATCH), 256, 0, stream>>>(
      E, Vpp, out, b_out, L, NTOK, NTOK, NTOK, DIM,
      (long)NTOK * NTOK, (long)DIM * NTOK, (long)NTOK * DIM);
}

// Round 11
// 260.637 us; speedup vs baseline: 1.0941x; 1.0634x over previous
//
#include <hip/hip_runtime.h>

// ---------------------------------------------------------------------------
// SelfAttentionBlock: B=4, N=2048, D=1024.
//   QKV = X @ Wqkv^T                   (8192x1024)@(3072x1024)^T   [core32-dbuf]
//   E_b = exp(Q_b @ K_b^T * 0.125)     bf16 + row-sum L (atomic)   [core16, fused]
//   V''_b = Wout @ V_b^T               (1024x2048) per batch       [core16, fused]
//   out_b = (E_b @ V''_b^T) / L + b    fp32                        [core32-dbuf]
// R18: combine the measured-best core PER DISPATCH (10-round ledger):
//  - sv: R17's 16x16x32 1-phase core -> 72.5us (best; 0 conflicts, VGPR 92)
//  - qkv/out: R3's 32x32x16 2-phase dbuf core -> non-sv 186.7us (best;
//    dbuf's ILP prefetch pays on long-K/low-TLP out-GEMM, K=2048/512 blocks)
// No new structure. Occupancy theory refuted in R17 (faster at lower occ);
// schedule/conflict/BW/barrier theories all previously nulled — this round
// is pure composition of verified artifacts.
// ---------------------------------------------------------------------------

typedef __bf16 bf16;
typedef __attribute__((ext_vector_type(8))) __bf16 bf16x8;
typedef __attribute__((ext_vector_type(4))) __bf16 bf16x4;
typedef __attribute__((ext_vector_type(16))) float f32x16;
typedef __attribute__((ext_vector_type(4))) float f32x4;

#define BATCH 4
#define NTOK  2048
#define DIM   1024
#define MROWS (BATCH * NTOK)   // 8192
#define QKVC  (3 * DIM)        // 3072

__device__ __forceinline__ void async16(const bf16* g, bf16* l) {
  __builtin_amdgcn_global_load_lds(
      (const __attribute__((address_space(1))) void*)g,
      (__attribute__((address_space(3))) void*)l, 16, 0, 0);
}

// ---------------------------------------------------------------------------
// prep: three fp32->bf16 converts + L zero
// ---------------------------------------------------------------------------
__device__ __forceinline__ void cvt4(const float* in, bf16* out, int i4) {
  float4 f = *(const float4*)(in + i4 * 4);
  bf16x4 o;
  o.x = (bf16)f.x; o.y = (bf16)f.y; o.z = (bf16)f.z; o.w = (bf16)f.w;
  *(bf16x4*)(out + i4 * 4) = o;
}

__global__ void prep(const float* __restrict__ x, const float* __restrict__ wqkv,
                     const float* __restrict__ wout,
                     bf16* __restrict__ Xbf, bf16* __restrict__ Wqkvb,
                     bf16* __restrict__ Woutb, float* __restrict__ L) {
  const int nx = MROWS * DIM / 4, nq = QKVC * DIM / 4, nw = DIM * DIM / 4;
  const int nl = BATCH * NTOK / 4;
  int i = blockIdx.x * blockDim.x + threadIdx.x;
  if (i < nx) cvt4(x, Xbf, i);
  else if (i < nx + nq) cvt4(wqkv, Wqkvb, i - nx);
  else if (i < nx + nq + nw) cvt4(wout, Woutb, i - nx - nq);
  else if (i < nx + nq + nw + nl) {
    float4 z = {0.f, 0.f, 0.f, 0.f};
    *(float4*)(L + (i - nx - nq - nw) * 4) = z;
  }
}

// ===========================================================================
// core32-dbuf (R3, verified): 128x128 / BK=64 / 32x32x16 / 2-phase dbuf.
// 4 waves 2x2, wave 64x64 = 2x2 of 32x32. A-frag: A[m=lane&31][k=8*(l>>5)+e].
// C/D: col=lane&31, row=(reg&3)+8*(reg>>2)+4*(lane>>5).
// LDS [128][64], slot c of row r holds chunk c^(r&7) (swizzle on global src).
// ===========================================================================
struct Core32 {
  const bf16 *ga[4], *gb[4];
  int sIdx[4];
  int wm, wn, l31, half;
};

__device__ __forceinline__ Core32 c32_setup(const bf16* A, const bf16* Bm,
                                            int lda, int ldb,
                                            long rowA, long rowB) {
  Core32 g;
  const int tid = threadIdx.x;
  const int wave = tid >> 6, lane = tid & 63;
  g.wm = (wave >> 1) << 6;
  g.wn = (wave & 1) << 6;
  g.l31 = lane & 31;
  g.half = lane >> 5;
  const int srow = tid >> 3;
  const int sc   = tid & 7;
  const int scol = (sc ^ (srow & 7)) << 3;
#pragma unroll
  for (int seg = 0; seg < 4; ++seg) {
    g.ga[seg] = A  + (rowA + srow + 32 * seg) * (long)lda + scol;
    g.gb[seg] = Bm + (rowB + srow + 32 * seg) * (long)ldb + scol;
    g.sIdx[seg] = (srow + 32 * seg) * 64 + sc * 8;
  }
  return g;
}

__device__ __forceinline__ void c32_stage(const Core32& g, int kt,
                                          bf16* As, bf16* Bs) {
#pragma unroll
  for (int seg = 0; seg < 4; ++seg) {
    async16(g.ga[seg] + kt, As + g.sIdx[seg]);
    async16(g.gb[seg] + kt, Bs + g.sIdx[seg]);
  }
}

__device__ __forceinline__ void c32_compute(const Core32& g,
                                            const bf16* As, const bf16* Bs,
                                            f32x16 acc[2][2]) {
  const int sw = g.l31 & 7;
  bf16x8 af[2][4], bfm[2][4];
#pragma unroll
  for (int ti = 0; ti < 2; ++ti)
#pragma unroll
    for (int s = 0; s < 4; ++s)
      af[ti][s] = *(const bf16x8*)&As[(g.wm + ti * 32 + g.l31) * 64 + ((s * 2 + g.half) ^ sw) * 8];
#pragma unroll
  for (int tj = 0; tj < 2; ++tj)
#pragma unroll
    for (int s = 0; s < 4; ++s)
      bfm[tj][s] = *(const bf16x8*)&Bs[(g.wn + tj * 32 + g.l31) * 64 + ((s * 2 + g.half) ^ sw) * 8];

#pragma unroll
  for (int s = 0; s < 4; ++s)
#pragma unroll
    for (int ti = 0; ti < 2; ++ti)
#pragma unroll
      for (int tj = 0; tj < 2; ++tj)
        acc[ti][tj] = __builtin_amdgcn_mfma_f32_32x32x16_bf16(
            af[ti][s], bfm[tj][s], acc[ti][tj], 0, 0, 0);
}

__device__ __forceinline__ void c32_sync() {
  asm volatile("s_waitcnt vmcnt(0) lgkmcnt(0)" ::: "memory");
  __builtin_amdgcn_s_barrier();
}

// 2-phase double-buffered K-loop (stage(t+1) before compute(t); 1 sync/tile)
__device__ __forceinline__ void c32_kloop(const Core32& g, int K,
                                          bf16* As0, bf16* Bs0,
                                          bf16* As1, bf16* Bs1,
                                          f32x16 acc[2][2]) {
  c32_stage(g, 0, As0, Bs0);
  c32_sync();
  const int nt = K >> 6;            // 16 or 32 — always even here
#pragma unroll 1
  for (int t2 = 0; t2 < nt / 2 - 1; ++t2) {
    c32_stage(g, (2 * t2 + 1) * 64, As1, Bs1);
    c32_compute(g, As0, Bs0, acc);
    c32_sync();
    c32_stage(g, (2 * t2 + 2) * 64, As0, Bs0);
    c32_compute(g, As1, Bs1, acc);
    c32_sync();
  }
  c32_stage(g, (nt - 1) * 64, As1, Bs1);
  c32_compute(g, As0, Bs0, acc);
  c32_sync();
  c32_compute(g, As1, Bs1, acc);
}

// MODE 0: store bf16. MODE 2: store fp32 acc/L[row] + bias[col].
template <int MODE>
__launch_bounds__(256)
__global__ void gemm_bt(const bf16* __restrict__ Aroot, const bf16* __restrict__ Broot,
                        void* __restrict__ Croot, const float* __restrict__ bias,
                        const float* __restrict__ Lroot,
                        int K, int lda, int ldb, int ldc,
                        long strideA, long strideB, long strideC) {
  const bf16* A  = Aroot + (long)blockIdx.z * strideA;
  const bf16* Bm = Broot + (long)blockIdx.z * strideB;
  __shared__ alignas(16) bf16 As0[128 * 64];
  __shared__ alignas(16) bf16 Bs0[128 * 64];
  __shared__ alignas(16) bf16 As1[128 * 64];
  __shared__ alignas(16) bf16 Bs1[128 * 64];

  const long rowA = (long)blockIdx.y * 128;
  const long rowB = (long)blockIdx.x * 128;
  Core32 g = c32_setup(A, Bm, lda, ldb, rowA, rowB);

  f32x16 acc[2][2] = {};
  c32_kloop(g, K, As0, Bs0, As1, Bs1, acc);

  if constexpr (MODE == 0) {
    bf16* C = (bf16*)Croot + (long)blockIdx.z * strideC;
#pragma unroll
    for (int ti = 0; ti < 2; ++ti)
#pragma unroll
      for (int tj = 0; tj < 2; ++tj) {
        const long col = rowB + g.wn + tj * 32 + g.l31;
#pragma unroll
        for (int r = 0; r < 16; ++r) {
          const long row = rowA + g.wm + ti * 32 + (r & 3) + 8 * (r >> 2) + 4 * g.half;
          C[row * (long)ldc + col] = (bf16)acc[ti][tj][r];
        }
      }
  } else {
    float* C = (float*)Croot + (long)blockIdx.z * strideC;
    const float* L = Lroot + (long)blockIdx.z * NTOK;
#pragma unroll
    for (int ti = 0; ti < 2; ++ti) {
#pragma unroll
      for (int r = 0; r < 16; ++r) {
        const long row = rowA + g.wm + ti * 32 + (r & 3) + 8 * (r >> 2) + 4 * g.half;
        const float inv = 1.0f / L[row];
#pragma unroll
        for (int tj = 0; tj < 2; ++tj) {
          const long col = rowB + g.wn + tj * 32 + g.l31;
          C[row * (long)ldc + col] = acc[ti][tj][r] * inv + bias[col];
        }
      }
    }
  }
}

// ===========================================================================
// core16 (R17, verified): 128x128 / BK=64 / 16x16x32 / 1-phase. 4 waves 2x2,
// wave 64x64 = 4x4 of 16x16. acc[4][4] f32x4 (64 AGPR). A/B lane l:
// m(or n)=l&15, k=8*(l>>4)+e. C/D: col=l&15, row=(l>>4)*4+r.
// Read: row&7 = l&7 = sw; global chunk g = ks*4+(l>>4) -> slot g^sw.
// ===========================================================================
struct Core16 {
  const bf16 *ga[4], *gb[4];
  int sIdx[4];
  int wm, wn, l15, kq;
};

__device__ __forceinline__ Core16 c16_setup(const bf16* A, const bf16* Bm,
                                            int lda, int ldb,
                                            long rowA, long rowB) {
  Core16 g;
  const int tid = threadIdx.x;
  const int wave = tid >> 6, lane = tid & 63;
  g.wm = (wave >> 1) << 6;
  g.wn = (wave & 1) << 6;
  g.l15 = lane & 15;
  g.kq  = lane >> 4;                       // 0..3
  const int srow = tid >> 3;               // 0..31
  const int sc   = tid & 7;                // physical slot
  const int scol = (sc ^ (srow & 7)) << 3; // swizzled global chunk * 8
#pragma unroll
  for (int seg = 0; seg < 4; ++seg) {
    g.ga[seg] = A  + (rowA + srow + 32 * seg) * (long)lda + scol;
    g.gb[seg] = Bm + (rowB + srow + 32 * seg) * (long)ldb + scol;
    g.sIdx[seg] = (srow + 32 * seg) * 64 + sc * 8;
  }
  return g;
}

__device__ __forceinline__ void c16_kloop(const Core16& g, int K,
                                          bf16* As, bf16* Bs, f32x4 acc[4][4]) {
  const int sw = g.l15 & 7;
  for (int kt = 0; kt < K; kt += 64) {
#pragma unroll
    for (int seg = 0; seg < 4; ++seg) {
      async16(g.ga[seg] + kt, As + g.sIdx[seg]);
      async16(g.gb[seg] + kt, Bs + g.sIdx[seg]);
    }
    __syncthreads();

#pragma unroll
    for (int ks = 0; ks < 2; ++ks) {
      const int slot = ((ks * 4 + g.kq) ^ sw) * 8;
      bf16x8 af[4], bfm[4];
#pragma unroll
      for (int ti = 0; ti < 4; ++ti)
        af[ti] = *(const bf16x8*)&As[(g.wm + ti * 16 + g.l15) * 64 + slot];
#pragma unroll
      for (int tj = 0; tj < 4; ++tj)
        bfm[tj] = *(const bf16x8*)&Bs[(g.wn + tj * 16 + g.l15) * 64 + slot];
#pragma unroll
      for (int ti = 0; ti < 4; ++ti)
#pragma unroll
        for (int tj = 0; tj < 4; ++tj)
          acc[ti][tj] = __builtin_amdgcn_mfma_f32_16x16x32_bf16(
              af[ti], bfm[tj], acc[ti][tj], 0, 0, 0);
    }

    __syncthreads();
  }
}

// ---------------------------------------------------------------------------
// Fused dispatch (core16): z<4 -> E_b = exp(Q_b@K_b^T/8) + row-sum L;
//                          z>=4 -> V''_b = Wout @ V_b^T (blockIdx.y>=8 idle).
// ---------------------------------------------------------------------------
__launch_bounds__(256)
__global__ void gemm_sv(const bf16* __restrict__ QKV, const bf16* __restrict__ Wout,
                        bf16* __restrict__ E, bf16* __restrict__ Vpp,
                        float* __restrict__ Lroot) {
  __shared__ alignas(16) bf16 As[128 * 64];
  __shared__ alignas(16) bf16 Bs[128 * 64];

  const int z = blockIdx.z;
  if (z < 4) {
    // ---- E-GEMM: A=Q, B=K rows of QKV batch z ----
    const bf16* A  = QKV + (long)z * NTOK * QKVC;
    const bf16* Bm = A + DIM;
    const long rowA = (long)blockIdx.y * 128;
    const long rowB = (long)blockIdx.x * 128;
    Core16 g = c16_setup(A, Bm, QKVC, QKVC, rowA, rowB);
    f32x4 acc[4][4] = {};
    c16_kloop(g, DIM, As, Bs, acc);

    bf16* C = E + (long)z * NTOK * NTOK;
    float* L = Lroot + (long)z * NTOK;
#pragma unroll
    for (int ti = 0; ti < 4; ++ti) {
#pragma unroll
      for (int r = 0; r < 4; ++r) {
        const long row = rowA + g.wm + ti * 16 + g.kq * 4 + r;
        float psum = 0.f;
#pragma unroll
        for (int tj = 0; tj < 4; ++tj) {
          const long col = rowB + g.wn + tj * 16 + g.l15;
          float e = __expf(acc[ti][tj][r] * 0.125f);
          bf16 eb = (bf16)e;
          C[row * (long)NTOK + col] = eb;
          psum += (float)eb;   // sum what downstream consumes
        }
        // reduce over the 16-lane group (same row: lanes differ in l15 only)
#pragma unroll
        for (int off = 8; off >= 1; off >>= 1) psum += __shfl_xor(psum, off, 64);
        if (g.l15 == 0) atomicAdd(&L[row], psum);
      }
    }
  } else {
    if (blockIdx.y >= 8) return;   // V'' output is 1024 rows = 8 row-tiles
    // ---- V''-GEMM: A=Wout (1024x1024), B=V rows of QKV batch z-4 ----
    const int b = z - 4;
    const bf16* Bm = QKV + (long)b * NTOK * QKVC + 2 * DIM;
    const long rowA = (long)blockIdx.y * 128;
    const long rowB = (long)blockIdx.x * 128;
    Core16 g = c16_setup(Wout, Bm, DIM, QKVC, rowA, rowB);
    f32x4 acc[4][4] = {};
    c16_kloop(g, DIM, As, Bs, acc);

    bf16* C = Vpp + (long)b * DIM * NTOK;
#pragma unroll
    for (int ti = 0; ti < 4; ++ti)
#pragma unroll
      for (int tj = 0; tj < 4; ++tj) {
        const long col = rowB + g.wn + tj * 16 + g.l15;
#pragma unroll
        for (int r = 0; r < 4; ++r) {
          const long row = rowA + g.wm + ti * 16 + g.kq * 4 + r;
          C[row * (long)NTOK + col] = (bf16)acc[ti][tj][r];
        }
      }
  }
}

// ---------------------------------------------------------------------------
extern "C" void kernel_launch(void* const* d_in, const int* in_sizes, int n_in,
                              void* d_out, int out_size, void* d_ws, size_t ws_size,
                              hipStream_t stream) {
  const float* x      = (const float*)d_in[0];   // (4,2048,1024)
  const float* w_qkv  = (const float*)d_in[1];   // (3072,1024)
  const float* w_out  = (const float*)d_in[2];   // (1024,1024)
  const float* b_out  = (const float*)d_in[3];   // (1024,)
  float* out = (float*)d_out;                    // (4,2048,1024) fp32

  // workspace layout (bytes) — total ~120 MiB
  char* w = (char*)d_ws;
  bf16*  Xbf   = (bf16*)(w);                          // 8192*1024*2   = 16 MiB
  bf16*  Wqkvb = (bf16*)(w + 16777216);               // 3072*1024*2   =  6 MiB
  bf16*  Woutb = (bf16*)(w + 23068672);               // 1024*1024*2   =  2 MiB
  bf16*  QKV   = (bf16*)(w + 25165824);               // 8192*3072*2   = 48 MiB
  bf16*  E     = (bf16*)(w + 75497472);               // 4*2048*2048*2 = 32 MiB
  bf16*  Vpp   = (bf16*)(w + 109051904);              // 4*1024*2048*2 = 16 MiB
  float* L     = (float*)(w + 125829120);             // 4*2048*4      = 32 KiB

  // 1) one prep dispatch: converts + L zero
  {
    const int n4 = MROWS * DIM / 4 + QKVC * DIM / 4 + DIM * DIM / 4 + BATCH * NTOK / 4;
    prep<<<(n4 + 255) / 256, 256, 0, stream>>>(x, w_qkv, w_out, Xbf, Wqkvb, Woutb, L);
  }

  // 2) QKV = X @ Wqkv^T -> bf16 (8192 x 3072); core32-dbuf
  gemm_bt<0><<<dim3(QKVC / 128, MROWS / 128, 1), 256, 0, stream>>>(
      Xbf, Wqkvb, QKV, nullptr, nullptr, DIM, DIM, DIM, QKVC, 0, 0, 0);

  // 3) fused: E_b = exp(Q_b@K_b^T/8) + L row-sums AND V''_b = Wout @ V_b^T
  //    core16 (best sv, R17)
  gemm_sv<<<dim3(NTOK / 128, NTOK / 128, 2 * BATCH), 256, 0, stream>>>(
      QKV, Woutb, E, Vpp, L);

  // 4) out_b = (E_b @ V''_b^T)/L + b_out -> fp32; core32-dbuf
  gemm_bt<2><<<dim3(DIM / 128, NTOK / 128, BATCH), 256, 0, stream>>>(
      E, Vpp, out, b_out, L, NTOK, NTOK, NTOK, DIM,
      (long)NTOK * NTOK, (long)DIM * NTOK, (long)NTOK * DIM);
}